// Round 1
// baseline (1198.439 us; speedup 1.0000x reference)
//
#include <hip/hip_runtime.h>
#include <cstdint>
#include <cstddef>

// ---------------- CSR build ----------------

__global__ void k_detect64(const unsigned int* ei, int e, int* is64) {
    // If edge_index is int64 (values < 2^31, nonneg), every odd 32-bit word is 0.
    __shared__ int nonzero;
    if (threadIdx.x == 0) nonzero = 0;
    __syncthreads();
    for (int i = threadIdx.x; i < 4096; i += blockDim.x) {
        size_t k = (size_t)((unsigned long long)i * (unsigned long long)e / 4096ull);
        if (ei[2 * k + 1] != 0u) nonzero = 1;   // racy OR, fine
    }
    __syncthreads();
    if (threadIdx.x == 0) *is64 = nonzero ? 0 : 1;
}

__global__ void k_cvt_edges(const void* ei_raw, int e, const int* is64,
                            int* __restrict__ src32, int* __restrict__ dst32) {
    int i = blockIdx.x * blockDim.x + threadIdx.x;
    if (i >= e) return;
    if (*is64) {
        const long long* p = (const long long*)ei_raw;
        src32[i] = (int)p[i];
        dst32[i] = (int)p[(size_t)e + i];
    } else {
        const int* p = (const int*)ei_raw;
        src32[i] = p[i];
        dst32[i] = p[(size_t)e + i];
    }
}

__global__ void k_init_deg(int* deg, int n) {
    int i = blockIdx.x * blockDim.x + threadIdx.x;
    if (i < n) deg[i] = 1;   // self-loop
}

__global__ void k_count(const int* __restrict__ dst, int e, int* __restrict__ deg) {
    int i = blockIdx.x * blockDim.x + threadIdx.x;
    if (i < e) atomicAdd(&deg[dst[i]], 1);
}

__global__ void k_dinv(const int* __restrict__ deg, float* __restrict__ dinv, int n) {
    int i = blockIdx.x * blockDim.x + threadIdx.x;
    if (i < n) dinv[i] = rsqrtf((float)deg[i]);
}

// Exclusive scan of (deg[i]-1) over n elements, single block of 1024 threads.
__global__ void k_scan(const int* __restrict__ deg, int* __restrict__ row_ptr,
                       int* __restrict__ cursor, int n) {
    __shared__ int partial[1024];
    int t = threadIdx.x;
    int chunk = (n + 1023) / 1024;
    int lo = t * chunk;
    int hi = lo + chunk; if (hi > n) hi = n;
    int s = 0;
    for (int i = lo; i < hi; ++i) s += deg[i] - 1;
    partial[t] = s;
    __syncthreads();
    for (int d = 1; d < 1024; d <<= 1) {
        int v = (t >= d) ? partial[t - d] : 0;
        __syncthreads();
        partial[t] += v;
        __syncthreads();
    }
    int base = (t == 0) ? 0 : partial[t - 1];
    for (int i = lo; i < hi; ++i) {
        row_ptr[i] = base;
        cursor[i]  = base;
        base += deg[i] - 1;
    }
    if (t == 1023) row_ptr[n] = base;  // == total edge count
}

__global__ void k_scatter(const int* __restrict__ src, const int* __restrict__ dst, int e,
                          int* __restrict__ cursor, int* __restrict__ src_sorted) {
    int i = blockIdx.x * blockDim.x + threadIdx.x;
    if (i >= e) return;
    int pos = atomicAdd(&cursor[dst[i]], 1);
    src_sorted[pos] = src[i];
}

// ---------------- GEMMs (f32 VALU, LDS-tiled), output pre-scaled by dinv[row] ----------------

// C[m][c] = dinv[m] * sum_k A[m][k]*W[k][c], K=128, N=128. Tile 64x128, block 256.
__global__ __launch_bounds__(256) void k_gemm128(const float* __restrict__ A,
                                                 const float* __restrict__ W,
                                                 const float* __restrict__ dinv,
                                                 float* __restrict__ C, int M) {
    __shared__ float sA[64][36];     // +4 pad: kills row-stride bank aliasing
    __shared__ float sW[32][128];
    int tid = threadIdx.x;
    int tx = tid & 15;   // cols tx*8 .. +7
    int ty = tid >> 4;   // rows ty*4 .. +3
    int row0 = blockIdx.x * 64;
    float acc[4][8] = {};
    for (int k0 = 0; k0 < 128; k0 += 32) {
        __syncthreads();
        // stage A tile 64x32 (512 float4, 2/thread)
        for (int i = tid; i < 512; i += 256) {
            int r = i >> 3, c4 = i & 7;
            float4 v = {0.f, 0.f, 0.f, 0.f};
            int gr = row0 + r;
            if (gr < M) v = *reinterpret_cast<const float4*>(&A[(size_t)gr * 128 + k0 + c4 * 4]);
            *reinterpret_cast<float4*>(&sA[r][c4 * 4]) = v;
        }
        // stage W tile 32x128 (1024 float4, 4/thread)
        for (int i = tid; i < 1024; i += 256) {
            int r = i >> 5, c4 = i & 31;
            *reinterpret_cast<float4*>(&sW[r][c4 * 4]) =
                *reinterpret_cast<const float4*>(&W[(size_t)(k0 + r) * 128 + c4 * 4]);
        }
        __syncthreads();
        #pragma unroll
        for (int k = 0; k < 32; k += 4) {
            float4 a[4];
            #pragma unroll
            for (int r = 0; r < 4; ++r)
                a[r] = *reinterpret_cast<const float4*>(&sA[ty * 4 + r][k]);
            #pragma unroll
            for (int kk = 0; kk < 4; ++kk) {
                float4 w0 = *reinterpret_cast<const float4*>(&sW[k + kk][tx * 8]);
                float4 w1 = *reinterpret_cast<const float4*>(&sW[k + kk][tx * 8 + 4]);
                #pragma unroll
                for (int r = 0; r < 4; ++r) {
                    float av = (&a[r].x)[kk];
                    acc[r][0] += av * w0.x; acc[r][1] += av * w0.y;
                    acc[r][2] += av * w0.z; acc[r][3] += av * w0.w;
                    acc[r][4] += av * w1.x; acc[r][5] += av * w1.y;
                    acc[r][6] += av * w1.z; acc[r][7] += av * w1.w;
                }
            }
        }
    }
    #pragma unroll
    for (int r = 0; r < 4; ++r) {
        int gr = row0 + ty * 4 + r;
        if (gr < M) {
            float di = dinv[gr];
            float4 o0 = {acc[r][0] * di, acc[r][1] * di, acc[r][2] * di, acc[r][3] * di};
            float4 o1 = {acc[r][4] * di, acc[r][5] * di, acc[r][6] * di, acc[r][7] * di};
            *reinterpret_cast<float4*>(&C[(size_t)gr * 128 + tx * 8])     = o0;
            *reinterpret_cast<float4*>(&C[(size_t)gr * 128 + tx * 8 + 4]) = o1;
        }
    }
}

// C[m][c] = dinv[m] * sum_k A[m][k]*W[k][c], K=128, N=64. Tile 64x64, block 256.
__global__ __launch_bounds__(256) void k_gemm64(const float* __restrict__ A,
                                                const float* __restrict__ W,
                                                const float* __restrict__ dinv,
                                                float* __restrict__ C, int M) {
    __shared__ float sA[64][36];
    __shared__ float sW[32][64];
    int tid = threadIdx.x;
    int tx = tid & 15;   // cols tx*4 .. +3
    int ty = tid >> 4;   // rows ty*4 .. +3
    int row0 = blockIdx.x * 64;
    float acc[4][4] = {};
    for (int k0 = 0; k0 < 128; k0 += 32) {
        __syncthreads();
        for (int i = tid; i < 512; i += 256) {
            int r = i >> 3, c4 = i & 7;
            float4 v = {0.f, 0.f, 0.f, 0.f};
            int gr = row0 + r;
            if (gr < M) v = *reinterpret_cast<const float4*>(&A[(size_t)gr * 128 + k0 + c4 * 4]);
            *reinterpret_cast<float4*>(&sA[r][c4 * 4]) = v;
        }
        for (int i = tid; i < 512; i += 256) {
            int r = i >> 4, c4 = i & 15;
            *reinterpret_cast<float4*>(&sW[r][c4 * 4]) =
                *reinterpret_cast<const float4*>(&W[(size_t)(k0 + r) * 64 + c4 * 4]);
        }
        __syncthreads();
        #pragma unroll
        for (int k = 0; k < 32; k += 4) {
            float4 a[4];
            #pragma unroll
            for (int r = 0; r < 4; ++r)
                a[r] = *reinterpret_cast<const float4*>(&sA[ty * 4 + r][k]);
            #pragma unroll
            for (int kk = 0; kk < 4; ++kk) {
                float4 w = *reinterpret_cast<const float4*>(&sW[k + kk][tx * 4]);
                #pragma unroll
                for (int r = 0; r < 4; ++r) {
                    float av = (&a[r].x)[kk];
                    acc[r][0] += av * w.x; acc[r][1] += av * w.y;
                    acc[r][2] += av * w.z; acc[r][3] += av * w.w;
                }
            }
        }
    }
    #pragma unroll
    for (int r = 0; r < 4; ++r) {
        int gr = row0 + ty * 4 + r;
        if (gr < M) {
            float di = dinv[gr];
            float4 o = {acc[r][0] * di, acc[r][1] * di, acc[r][2] * di, acc[r][3] * di};
            *reinterpret_cast<float4*>(&C[(size_t)gr * 64 + tx * 4]) = o;
        }
    }
}

// ---------------- Aggregation (one block per node, channel per thread) ----------------

// h2[i][c] = relu( dinv[i]*(hs[i][c] + sum_{e in CSR[i]} hs[src_e][c]) + b1[c] )
__global__ __launch_bounds__(128) void k_agg1(const float* __restrict__ hs,
                                              const float* __restrict__ dinv,
                                              const int* __restrict__ row_ptr,
                                              const int* __restrict__ src_sorted,
                                              const float* __restrict__ b1,
                                              float* __restrict__ h2) {
    int i = blockIdx.x;
    int c = threadIdx.x;
    float acc = hs[(size_t)i * 128 + c];
    int lo = row_ptr[i], hi = row_ptr[i + 1];
    for (int e = lo; e < hi; ++e) {
        int s = src_sorted[e];
        acc += hs[(size_t)s * 128 + c];
    }
    float v = dinv[i] * acc + b1[c];
    h2[(size_t)i * 128 + c] = v > 0.f ? v : 0.f;
}

// out[i][c] = dinv[i]*(zs[i][c] + sum zs[src_e][c]) + b2[c]
__global__ __launch_bounds__(64) void k_agg2(const float* __restrict__ zs,
                                             const float* __restrict__ dinv,
                                             const int* __restrict__ row_ptr,
                                             const int* __restrict__ src_sorted,
                                             const float* __restrict__ b2,
                                             float* __restrict__ out) {
    int i = blockIdx.x;
    int c = threadIdx.x;
    float acc = zs[(size_t)i * 64 + c];
    int lo = row_ptr[i], hi = row_ptr[i + 1];
    for (int e = lo; e < hi; ++e) {
        int s = src_sorted[e];
        acc += zs[(size_t)s * 64 + c];
    }
    out[(size_t)i * 64 + c] = dinv[i] * acc + b2[c];
}

// ---------------- launch ----------------

static inline size_t alignup(size_t v) { return (v + 255) & ~(size_t)255; }

extern "C" void kernel_launch(void* const* d_in, const int* in_sizes, int n_in,
                              void* d_out, int out_size, void* d_ws, size_t ws_size,
                              hipStream_t stream) {
    const float* x  = (const float*)d_in[0];
    const void*  ei = d_in[1];
    const float* W1 = (const float*)d_in[2];
    const float* b1 = (const float*)d_in[3];
    const float* W2 = (const float*)d_in[4];
    const float* b2 = (const float*)d_in[5];

    const int n = in_sizes[0] / 128;   // 100000
    const int e = in_sizes[1] / 2;     // 3200000

    char* p = (char*)d_ws;
    auto take = [&](size_t bytes) { char* q = p; p += alignup(bytes); return q; };
    int*   is64       = (int*)  take(4);
    int*   src32      = (int*)  take((size_t)e * 4);
    int*   dst32      = (int*)  take((size_t)e * 4);
    int*   deg        = (int*)  take((size_t)n * 4);
    float* dinv       = (float*)take((size_t)n * 4);
    int*   row_ptr    = (int*)  take((size_t)(n + 1) * 4);
    int*   cursor     = (int*)  take((size_t)n * 4);
    int*   src_sorted = (int*)  take((size_t)e * 4);
    float* hs         = (float*)take((size_t)n * 128 * 4);
    float* h2         = (float*)take((size_t)n * 128 * 4);
    float* zs         = (float*)take((size_t)n * 64 * 4);
    if ((size_t)(p - (char*)d_ws) > ws_size) return;  // ws too small -> fail loudly

    const int nb_e = (e + 255) / 256;
    const int nb_n = (n + 255) / 256;

    k_detect64<<<1, 256, 0, stream>>>((const unsigned int*)ei, e, is64);
    k_cvt_edges<<<nb_e, 256, 0, stream>>>(ei, e, is64, src32, dst32);
    k_init_deg<<<nb_n, 256, 0, stream>>>(deg, n);
    k_count<<<nb_e, 256, 0, stream>>>(dst32, e, deg);
    k_dinv<<<nb_n, 256, 0, stream>>>(deg, dinv, n);
    k_scan<<<1, 1024, 0, stream>>>(deg, row_ptr, cursor, n);
    k_scatter<<<nb_e, 256, 0, stream>>>(src32, dst32, e, cursor, src_sorted);

    k_gemm128<<<(n + 63) / 64, 256, 0, stream>>>(x, W1, dinv, hs, n);
    k_agg1<<<n, 128, 0, stream>>>(hs, dinv, row_ptr, src_sorted, b1, h2);
    k_gemm64<<<(n + 63) / 64, 256, 0, stream>>>(h2, W2, dinv, zs, n);
    k_agg2<<<n, 64, 0, stream>>>(zs, dinv, row_ptr, src_sorted, b2, (float*)d_out);
}

// Round 2
// 1060.133 us; speedup vs baseline: 1.1305x; 1.1305x over previous
//
#include <hip/hip_runtime.h>
#include <cstdint>
#include <cstddef>

// ---------------- CSR build ----------------

__global__ void k_detect64(const unsigned int* ei, int e, int* is64) {
    // If edge_index is int64 (values < 2^31, nonneg), every odd 32-bit word is 0.
    __shared__ int nonzero;
    if (threadIdx.x == 0) nonzero = 0;
    __syncthreads();
    for (int i = threadIdx.x; i < 4096; i += blockDim.x) {
        size_t k = (size_t)((unsigned long long)i * (unsigned long long)e / 4096ull);
        if (ei[2 * k + 1] != 0u) nonzero = 1;   // racy OR, fine
    }
    __syncthreads();
    if (threadIdx.x == 0) *is64 = nonzero ? 0 : 1;
}

__global__ void k_init_deg(int* deg, int n) {
    int i = blockIdx.x * blockDim.x + threadIdx.x;
    if (i < n) deg[i] = 1;   // self-loop
}

// Fused convert + degree count (saves one full pass over the edge arrays).
__global__ void k_cvt_count(const void* ei_raw, int e, const int* is64,
                            int* __restrict__ src32, int* __restrict__ dst32,
                            int* __restrict__ deg) {
    int i = blockIdx.x * blockDim.x + threadIdx.x;
    if (i >= e) return;
    int s, d;
    if (*is64) {
        const long long* p = (const long long*)ei_raw;
        s = (int)p[i];
        d = (int)p[(size_t)e + i];
    } else {
        const int* p = (const int*)ei_raw;
        s = p[i];
        d = p[(size_t)e + i];
    }
    src32[i] = s;
    dst32[i] = d;
    atomicAdd(&deg[d], 1);
}

__global__ void k_dinv(const int* __restrict__ deg, float* __restrict__ dinv, int n) {
    int i = blockIdx.x * blockDim.x + threadIdx.x;
    if (i < n) dinv[i] = rsqrtf((float)deg[i]);
}

// Exclusive scan of (deg[i]-1) over n elements, single block of 1024 threads.
__global__ void k_scan(const int* __restrict__ deg, int* __restrict__ row_ptr,
                       int* __restrict__ cursor, int n) {
    __shared__ int partial[1024];
    int t = threadIdx.x;
    int chunk = (n + 1023) / 1024;
    int lo = t * chunk;
    int hi = lo + chunk; if (hi > n) hi = n;
    int s = 0;
    for (int i = lo; i < hi; ++i) s += deg[i] - 1;
    partial[t] = s;
    __syncthreads();
    for (int d = 1; d < 1024; d <<= 1) {
        int v = (t >= d) ? partial[t - d] : 0;
        __syncthreads();
        partial[t] += v;
        __syncthreads();
    }
    int base = (t == 0) ? 0 : partial[t - 1];
    for (int i = lo; i < hi; ++i) {
        row_ptr[i] = base;
        cursor[i]  = base;
        base += deg[i] - 1;
    }
    if (t == 1023) row_ptr[n] = base;  // == total edge count
}

__global__ void k_scatter(const int* __restrict__ src, const int* __restrict__ dst, int e,
                          int* __restrict__ cursor, int* __restrict__ src_sorted) {
    int i = blockIdx.x * blockDim.x + threadIdx.x;
    if (i >= e) return;
    int pos = atomicAdd(&cursor[dst[i]], 1);
    src_sorted[pos] = src[i];
}

// ---------------- GEMMs (f32 VALU, LDS-tiled), output pre-scaled by dinv[row] ----------------

// C[m][c] = dinv[m] * sum_k A[m][k]*W[k][c], K=128, N=128. Tile 64x128, block 256.
__global__ __launch_bounds__(256) void k_gemm128(const float* __restrict__ A,
                                                 const float* __restrict__ W,
                                                 const float* __restrict__ dinv,
                                                 float* __restrict__ C, int M) {
    __shared__ float sA[64][36];     // +4 pad: kills row-stride bank aliasing
    __shared__ float sW[32][128];
    int tid = threadIdx.x;
    int tx = tid & 15;   // cols tx*8 .. +7
    int ty = tid >> 4;   // rows ty*4 .. +3
    int row0 = blockIdx.x * 64;
    float acc[4][8] = {};
    for (int k0 = 0; k0 < 128; k0 += 32) {
        __syncthreads();
        // stage A tile 64x32 (512 float4, 2/thread)
        for (int i = tid; i < 512; i += 256) {
            int r = i >> 3, c4 = i & 7;
            float4 v = {0.f, 0.f, 0.f, 0.f};
            int gr = row0 + r;
            if (gr < M) v = *reinterpret_cast<const float4*>(&A[(size_t)gr * 128 + k0 + c4 * 4]);
            *reinterpret_cast<float4*>(&sA[r][c4 * 4]) = v;
        }
        // stage W tile 32x128 (1024 float4, 4/thread)
        for (int i = tid; i < 1024; i += 256) {
            int r = i >> 5, c4 = i & 31;
            *reinterpret_cast<float4*>(&sW[r][c4 * 4]) =
                *reinterpret_cast<const float4*>(&W[(size_t)(k0 + r) * 128 + c4 * 4]);
        }
        __syncthreads();
        #pragma unroll
        for (int k = 0; k < 32; k += 4) {
            float4 a[4];
            #pragma unroll
            for (int r = 0; r < 4; ++r)
                a[r] = *reinterpret_cast<const float4*>(&sA[ty * 4 + r][k]);
            #pragma unroll
            for (int kk = 0; kk < 4; ++kk) {
                float4 w0 = *reinterpret_cast<const float4*>(&sW[k + kk][tx * 8]);
                float4 w1 = *reinterpret_cast<const float4*>(&sW[k + kk][tx * 8 + 4]);
                #pragma unroll
                for (int r = 0; r < 4; ++r) {
                    float av = (&a[r].x)[kk];
                    acc[r][0] += av * w0.x; acc[r][1] += av * w0.y;
                    acc[r][2] += av * w0.z; acc[r][3] += av * w0.w;
                    acc[r][4] += av * w1.x; acc[r][5] += av * w1.y;
                    acc[r][6] += av * w1.z; acc[r][7] += av * w1.w;
                }
            }
        }
    }
    #pragma unroll
    for (int r = 0; r < 4; ++r) {
        int gr = row0 + ty * 4 + r;
        if (gr < M) {
            float di = dinv[gr];
            float4 o0 = {acc[r][0] * di, acc[r][1] * di, acc[r][2] * di, acc[r][3] * di};
            float4 o1 = {acc[r][4] * di, acc[r][5] * di, acc[r][6] * di, acc[r][7] * di};
            *reinterpret_cast<float4*>(&C[(size_t)gr * 128 + tx * 8])     = o0;
            *reinterpret_cast<float4*>(&C[(size_t)gr * 128 + tx * 8 + 4]) = o1;
        }
    }
}

// C[m][c] = dinv[m] * sum_k A[m][k]*W[k][c], K=128, N=64. Tile 64x64, block 256.
__global__ __launch_bounds__(256) void k_gemm64(const float* __restrict__ A,
                                                const float* __restrict__ W,
                                                const float* __restrict__ dinv,
                                                float* __restrict__ C, int M) {
    __shared__ float sA[64][36];
    __shared__ float sW[32][64];
    int tid = threadIdx.x;
    int tx = tid & 15;   // cols tx*4 .. +3
    int ty = tid >> 4;   // rows ty*4 .. +3
    int row0 = blockIdx.x * 64;
    float acc[4][4] = {};
    for (int k0 = 0; k0 < 128; k0 += 32) {
        __syncthreads();
        for (int i = tid; i < 512; i += 256) {
            int r = i >> 3, c4 = i & 7;
            float4 v = {0.f, 0.f, 0.f, 0.f};
            int gr = row0 + r;
            if (gr < M) v = *reinterpret_cast<const float4*>(&A[(size_t)gr * 128 + k0 + c4 * 4]);
            *reinterpret_cast<float4*>(&sA[r][c4 * 4]) = v;
        }
        for (int i = tid; i < 512; i += 256) {
            int r = i >> 4, c4 = i & 15;
            *reinterpret_cast<float4*>(&sW[r][c4 * 4]) =
                *reinterpret_cast<const float4*>(&W[(size_t)(k0 + r) * 64 + c4 * 4]);
        }
        __syncthreads();
        #pragma unroll
        for (int k = 0; k < 32; k += 4) {
            float4 a[4];
            #pragma unroll
            for (int r = 0; r < 4; ++r)
                a[r] = *reinterpret_cast<const float4*>(&sA[ty * 4 + r][k]);
            #pragma unroll
            for (int kk = 0; kk < 4; ++kk) {
                float4 w = *reinterpret_cast<const float4*>(&sW[k + kk][tx * 4]);
                #pragma unroll
                for (int r = 0; r < 4; ++r) {
                    float av = (&a[r].x)[kk];
                    acc[r][0] += av * w.x; acc[r][1] += av * w.y;
                    acc[r][2] += av * w.z; acc[r][3] += av * w.w;
                }
            }
        }
    }
    #pragma unroll
    for (int r = 0; r < 4; ++r) {
        int gr = row0 + ty * 4 + r;
        if (gr < M) {
            float di = dinv[gr];
            float4 o = {acc[r][0] * di, acc[r][1] * di, acc[r][2] * di, acc[r][3] * di};
            *reinterpret_cast<float4*>(&C[(size_t)gr * 64 + tx * 4]) = o;
        }
    }
}

// ---------------- Aggregation (one block per node, channel per thread) ----------------
// Unrolled x8: issue 8 independent row gathers before reducing -> 8 loads in
// flight per wave instead of 1 (the R1 kernel was a serial load->wait->add
// chain at VGPR_Count=8, VALUBusy 7.6%: pure latency bound).

// h2[i][c] = relu( dinv[i]*(hs[i][c] + sum_{e in CSR[i]} hs[src_e][c]) + b1[c] )
__global__ __launch_bounds__(128) void k_agg1(const float* __restrict__ hs,
                                              const float* __restrict__ dinv,
                                              const int* __restrict__ row_ptr,
                                              const int* __restrict__ src_sorted,
                                              const float* __restrict__ b1,
                                              float* __restrict__ h2) {
    int i = blockIdx.x;
    int c = threadIdx.x;
    float acc = hs[(size_t)i * 128 + c];
    int lo = row_ptr[i], hi = row_ptr[i + 1];
    int e = lo;
    for (; e + 8 <= hi; e += 8) {
        int s0 = src_sorted[e + 0], s1 = src_sorted[e + 1];
        int s2 = src_sorted[e + 2], s3 = src_sorted[e + 3];
        int s4 = src_sorted[e + 4], s5 = src_sorted[e + 5];
        int s6 = src_sorted[e + 6], s7 = src_sorted[e + 7];
        float v0 = hs[(size_t)s0 * 128 + c];
        float v1 = hs[(size_t)s1 * 128 + c];
        float v2 = hs[(size_t)s2 * 128 + c];
        float v3 = hs[(size_t)s3 * 128 + c];
        float v4 = hs[(size_t)s4 * 128 + c];
        float v5 = hs[(size_t)s5 * 128 + c];
        float v6 = hs[(size_t)s6 * 128 + c];
        float v7 = hs[(size_t)s7 * 128 + c];
        acc += ((v0 + v1) + (v2 + v3)) + ((v4 + v5) + (v6 + v7));
    }
    if (e + 4 <= hi) {
        int s0 = src_sorted[e + 0], s1 = src_sorted[e + 1];
        int s2 = src_sorted[e + 2], s3 = src_sorted[e + 3];
        float v0 = hs[(size_t)s0 * 128 + c];
        float v1 = hs[(size_t)s1 * 128 + c];
        float v2 = hs[(size_t)s2 * 128 + c];
        float v3 = hs[(size_t)s3 * 128 + c];
        acc += (v0 + v1) + (v2 + v3);
        e += 4;
    }
    for (; e < hi; ++e) {
        int s = src_sorted[e];
        acc += hs[(size_t)s * 128 + c];
    }
    float v = dinv[i] * acc + b1[c];
    h2[(size_t)i * 128 + c] = v > 0.f ? v : 0.f;
}

// out[i][c] = dinv[i]*(zs[i][c] + sum zs[src_e][c]) + b2[c]
__global__ __launch_bounds__(64) void k_agg2(const float* __restrict__ zs,
                                             const float* __restrict__ dinv,
                                             const int* __restrict__ row_ptr,
                                             const int* __restrict__ src_sorted,
                                             const float* __restrict__ b2,
                                             float* __restrict__ out) {
    int i = blockIdx.x;
    int c = threadIdx.x;
    float acc = zs[(size_t)i * 64 + c];
    int lo = row_ptr[i], hi = row_ptr[i + 1];
    int e = lo;
    for (; e + 8 <= hi; e += 8) {
        int s0 = src_sorted[e + 0], s1 = src_sorted[e + 1];
        int s2 = src_sorted[e + 2], s3 = src_sorted[e + 3];
        int s4 = src_sorted[e + 4], s5 = src_sorted[e + 5];
        int s6 = src_sorted[e + 6], s7 = src_sorted[e + 7];
        float v0 = zs[(size_t)s0 * 64 + c];
        float v1 = zs[(size_t)s1 * 64 + c];
        float v2 = zs[(size_t)s2 * 64 + c];
        float v3 = zs[(size_t)s3 * 64 + c];
        float v4 = zs[(size_t)s4 * 64 + c];
        float v5 = zs[(size_t)s5 * 64 + c];
        float v6 = zs[(size_t)s6 * 64 + c];
        float v7 = zs[(size_t)s7 * 64 + c];
        acc += ((v0 + v1) + (v2 + v3)) + ((v4 + v5) + (v6 + v7));
    }
    if (e + 4 <= hi) {
        int s0 = src_sorted[e + 0], s1 = src_sorted[e + 1];
        int s2 = src_sorted[e + 2], s3 = src_sorted[e + 3];
        float v0 = zs[(size_t)s0 * 64 + c];
        float v1 = zs[(size_t)s1 * 64 + c];
        float v2 = zs[(size_t)s2 * 64 + c];
        float v3 = zs[(size_t)s3 * 64 + c];
        acc += (v0 + v1) + (v2 + v3);
        e += 4;
    }
    for (; e < hi; ++e) {
        int s = src_sorted[e];
        acc += zs[(size_t)s * 64 + c];
    }
    out[(size_t)i * 64 + c] = dinv[i] * acc + b2[c];
}

// ---------------- launch ----------------

static inline size_t alignup(size_t v) { return (v + 255) & ~(size_t)255; }

extern "C" void kernel_launch(void* const* d_in, const int* in_sizes, int n_in,
                              void* d_out, int out_size, void* d_ws, size_t ws_size,
                              hipStream_t stream) {
    const float* x  = (const float*)d_in[0];
    const void*  ei = d_in[1];
    const float* W1 = (const float*)d_in[2];
    const float* b1 = (const float*)d_in[3];
    const float* W2 = (const float*)d_in[4];
    const float* b2 = (const float*)d_in[5];

    const int n = in_sizes[0] / 128;   // 100000
    const int e = in_sizes[1] / 2;     // 3200000

    char* p = (char*)d_ws;
    auto take = [&](size_t bytes) { char* q = p; p += alignup(bytes); return q; };
    int*   is64       = (int*)  take(4);
    int*   src32      = (int*)  take((size_t)e * 4);
    int*   dst32      = (int*)  take((size_t)e * 4);
    int*   deg        = (int*)  take((size_t)n * 4);
    float* dinv       = (float*)take((size_t)n * 4);
    int*   row_ptr    = (int*)  take((size_t)(n + 1) * 4);
    int*   cursor     = (int*)  take((size_t)n * 4);
    int*   src_sorted = (int*)  take((size_t)e * 4);
    float* hs         = (float*)take((size_t)n * 128 * 4);
    float* h2         = (float*)take((size_t)n * 128 * 4);
    float* zs         = (float*)take((size_t)n * 64 * 4);
    if ((size_t)(p - (char*)d_ws) > ws_size) return;  // ws too small -> fail loudly

    const int nb_e = (e + 255) / 256;
    const int nb_n = (n + 255) / 256;

    k_detect64<<<1, 256, 0, stream>>>((const unsigned int*)ei, e, is64);
    k_init_deg<<<nb_n, 256, 0, stream>>>(deg, n);
    k_cvt_count<<<nb_e, 256, 0, stream>>>(ei, e, is64, src32, dst32, deg);
    k_dinv<<<nb_n, 256, 0, stream>>>(deg, dinv, n);
    k_scan<<<1, 1024, 0, stream>>>(deg, row_ptr, cursor, n);
    k_scatter<<<nb_e, 256, 0, stream>>>(src32, dst32, e, cursor, src_sorted);

    k_gemm128<<<(n + 63) / 64, 256, 0, stream>>>(x, W1, dinv, hs, n);
    k_agg1<<<n, 128, 0, stream>>>(hs, dinv, row_ptr, src_sorted, b1, h2);
    k_gemm64<<<(n + 63) / 64, 256, 0, stream>>>(h2, W2, dinv, zs, n);
    k_agg2<<<n, 64, 0, stream>>>(zs, dinv, row_ptr, src_sorted, b2, (float*)d_out);
}

// Round 3
// 702.647 us; speedup vs baseline: 1.7056x; 1.5088x over previous
//
#include <hip/hip_runtime.h>
#include <cstdint>
#include <cstddef>

// ---------------- CSR build ----------------

__global__ void k_detect64(const unsigned int* ei, int e, int* is64) {
    // If edge_index is int64 (values < 2^31, nonneg), every odd 32-bit word is 0.
    __shared__ int nonzero;
    if (threadIdx.x == 0) nonzero = 0;
    __syncthreads();
    for (int i = threadIdx.x; i < 4096; i += blockDim.x) {
        size_t k = (size_t)((unsigned long long)i * (unsigned long long)e / 4096ull);
        if (ei[2 * k + 1] != 0u) nonzero = 1;   // racy OR, fine
    }
    __syncthreads();
    if (threadIdx.x == 0) *is64 = nonzero ? 0 : 1;
}

__global__ void k_init_deg(int* deg, int n) {
    int i = blockIdx.x * blockDim.x + threadIdx.x;
    if (i < n) deg[i] = 1;   // self-loop
}

// Fused convert + degree count (saves one full pass over the edge arrays).
__global__ void k_cvt_count(const void* ei_raw, int e, const int* is64,
                            int* __restrict__ src32, int* __restrict__ dst32,
                            int* __restrict__ deg) {
    int i = blockIdx.x * blockDim.x + threadIdx.x;
    if (i >= e) return;
    int s, d;
    if (*is64) {
        const long long* p = (const long long*)ei_raw;
        s = (int)p[i];
        d = (int)p[(size_t)e + i];
    } else {
        const int* p = (const int*)ei_raw;
        s = p[i];
        d = p[(size_t)e + i];
    }
    src32[i] = s;
    dst32[i] = d;
    atomicAdd(&deg[d], 1);
}

// --- 3-phase parallel exclusive scan of (deg[i]-1), 1024 elems/block ---
// Phase 1: per-block inclusive LDS scan -> row_ptr[i] = local exclusive,
//          gsum[b] = block total. Also computes dinv (reads deg anyway).
__global__ __launch_bounds__(1024) void k_scan1(const int* __restrict__ deg,
                                                int* __restrict__ row_ptr,
                                                int* __restrict__ gsum,
                                                float* __restrict__ dinv, int n) {
    __shared__ int s[1024];
    int t = threadIdx.x;
    int i = blockIdx.x * 1024 + t;
    int v = 0;
    if (i < n) {
        int d = deg[i];
        v = d - 1;
        dinv[i] = rsqrtf((float)d);
    }
    s[t] = v;
    __syncthreads();
    #pragma unroll
    for (int d = 1; d < 1024; d <<= 1) {
        int tmp = (t >= d) ? s[t - d] : 0;
        __syncthreads();
        s[t] += tmp;
        __syncthreads();
    }
    if (i < n) row_ptr[i] = s[t] - v;            // exclusive within block
    if (t == 1023) gsum[blockIdx.x] = s[1023];   // block total
}

// Phase 2: single block scans the (<=1024) block totals -> gbase (exclusive),
//          and writes row_ptr[n] = grand total.
__global__ __launch_bounds__(1024) void k_scan2(const int* __restrict__ gsum,
                                                int* __restrict__ gbase,
                                                int* __restrict__ row_ptr,
                                                int nb, int n) {
    __shared__ int s[1024];
    int t = threadIdx.x;
    int v = (t < nb) ? gsum[t] : 0;
    s[t] = v;
    __syncthreads();
    #pragma unroll
    for (int d = 1; d < 1024; d <<= 1) {
        int tmp = (t >= d) ? s[t - d] : 0;
        __syncthreads();
        s[t] += tmp;
        __syncthreads();
    }
    if (t < nb) gbase[t] = s[t] - v;
    if (t == 1023) row_ptr[n] = s[1023];
}

// Phase 3: add block base; materialize cursor.
__global__ void k_scan3(int* __restrict__ row_ptr, int* __restrict__ cursor,
                        const int* __restrict__ gbase, int n) {
    int i = blockIdx.x * blockDim.x + threadIdx.x;
    if (i >= n) return;
    int v = row_ptr[i] + gbase[i >> 10];
    row_ptr[i] = v;
    cursor[i]  = v;
}

// XCD-affinity scatter: block (blockIdx & 7) handles only dst nodes in its
// 1/8 node range, so each XCD's write window (~1.6 MB of src_sorted) fits
// its 4 MB L2 -> full-line writebacks instead of the 16x amplified random
// 4B stores of R2 (WRITE_SIZE 194 MB for a 12.8 MB payload, 733 GB/s).
// Reads are 8x re-streamed but coalesced and L3-resident. If block->XCD
// round-robin ever changes, this stays correct, only slower.
__global__ __launch_bounds__(256) void k_scatter_xcd(const int* __restrict__ src,
                                                     const int* __restrict__ dst, int e,
                                                     int* __restrict__ cursor,
                                                     int* __restrict__ src_sorted, int n) {
    int xcd = blockIdx.x & 7;
    int lo_node = (int)((long long)xcd * n / 8);
    int hi_node = (int)((long long)(xcd + 1) * n / 8);
    int nblk = gridDim.x >> 3;
    int bid  = blockIdx.x >> 3;
    int step = nblk * blockDim.x;
    for (int i = bid * blockDim.x + threadIdx.x; i < e; i += step) {
        int d = dst[i];
        int s = src[i];
        if (d >= lo_node && d < hi_node) {
            int pos = atomicAdd(&cursor[d], 1);
            src_sorted[pos] = s;
        }
    }
}

// ---------------- GEMMs (f32 VALU, LDS-tiled), output pre-scaled by dinv[row] ----------------

// C[m][c] = dinv[m] * sum_k A[m][k]*W[k][c], K=128, N=128. Tile 64x128, block 256.
__global__ __launch_bounds__(256) void k_gemm128(const float* __restrict__ A,
                                                 const float* __restrict__ W,
                                                 const float* __restrict__ dinv,
                                                 float* __restrict__ C, int M) {
    __shared__ float sA[64][36];     // +4 pad: kills row-stride bank aliasing
    __shared__ float sW[32][128];
    int tid = threadIdx.x;
    int tx = tid & 15;   // cols tx*8 .. +7
    int ty = tid >> 4;   // rows ty*4 .. +3
    int row0 = blockIdx.x * 64;
    float acc[4][8] = {};
    for (int k0 = 0; k0 < 128; k0 += 32) {
        __syncthreads();
        // stage A tile 64x32 (512 float4, 2/thread)
        for (int i = tid; i < 512; i += 256) {
            int r = i >> 3, c4 = i & 7;
            float4 v = {0.f, 0.f, 0.f, 0.f};
            int gr = row0 + r;
            if (gr < M) v = *reinterpret_cast<const float4*>(&A[(size_t)gr * 128 + k0 + c4 * 4]);
            *reinterpret_cast<float4*>(&sA[r][c4 * 4]) = v;
        }
        // stage W tile 32x128 (1024 float4, 4/thread)
        for (int i = tid; i < 1024; i += 256) {
            int r = i >> 5, c4 = i & 31;
            *reinterpret_cast<float4*>(&sW[r][c4 * 4]) =
                *reinterpret_cast<const float4*>(&W[(size_t)(k0 + r) * 128 + c4 * 4]);
        }
        __syncthreads();
        #pragma unroll
        for (int k = 0; k < 32; k += 4) {
            float4 a[4];
            #pragma unroll
            for (int r = 0; r < 4; ++r)
                a[r] = *reinterpret_cast<const float4*>(&sA[ty * 4 + r][k]);
            #pragma unroll
            for (int kk = 0; kk < 4; ++kk) {
                float4 w0 = *reinterpret_cast<const float4*>(&sW[k + kk][tx * 8]);
                float4 w1 = *reinterpret_cast<const float4*>(&sW[k + kk][tx * 8 + 4]);
                #pragma unroll
                for (int r = 0; r < 4; ++r) {
                    float av = (&a[r].x)[kk];
                    acc[r][0] += av * w0.x; acc[r][1] += av * w0.y;
                    acc[r][2] += av * w0.z; acc[r][3] += av * w0.w;
                    acc[r][4] += av * w1.x; acc[r][5] += av * w1.y;
                    acc[r][6] += av * w1.z; acc[r][7] += av * w1.w;
                }
            }
        }
    }
    #pragma unroll
    for (int r = 0; r < 4; ++r) {
        int gr = row0 + ty * 4 + r;
        if (gr < M) {
            float di = dinv[gr];
            float4 o0 = {acc[r][0] * di, acc[r][1] * di, acc[r][2] * di, acc[r][3] * di};
            float4 o1 = {acc[r][4] * di, acc[r][5] * di, acc[r][6] * di, acc[r][7] * di};
            *reinterpret_cast<float4*>(&C[(size_t)gr * 128 + tx * 8])     = o0;
            *reinterpret_cast<float4*>(&C[(size_t)gr * 128 + tx * 8 + 4]) = o1;
        }
    }
}

// C[m][c] = dinv[m] * sum_k A[m][k]*W[k][c], K=128, N=64. Tile 64x64, block 256.
__global__ __launch_bounds__(256) void k_gemm64(const float* __restrict__ A,
                                                const float* __restrict__ W,
                                                const float* __restrict__ dinv,
                                                float* __restrict__ C, int M) {
    __shared__ float sA[64][36];
    __shared__ float sW[32][64];
    int tid = threadIdx.x;
    int tx = tid & 15;   // cols tx*4 .. +3
    int ty = tid >> 4;   // rows ty*4 .. +3
    int row0 = blockIdx.x * 64;
    float acc[4][4] = {};
    for (int k0 = 0; k0 < 128; k0 += 32) {
        __syncthreads();
        for (int i = tid; i < 512; i += 256) {
            int r = i >> 3, c4 = i & 7;
            float4 v = {0.f, 0.f, 0.f, 0.f};
            int gr = row0 + r;
            if (gr < M) v = *reinterpret_cast<const float4*>(&A[(size_t)gr * 128 + k0 + c4 * 4]);
            *reinterpret_cast<float4*>(&sA[r][c4 * 4]) = v;
        }
        for (int i = tid; i < 512; i += 256) {
            int r = i >> 4, c4 = i & 15;
            *reinterpret_cast<float4*>(&sW[r][c4 * 4]) =
                *reinterpret_cast<const float4*>(&W[(size_t)(k0 + r) * 64 + c4 * 4]);
        }
        __syncthreads();
        #pragma unroll
        for (int k = 0; k < 32; k += 4) {
            float4 a[4];
            #pragma unroll
            for (int r = 0; r < 4; ++r)
                a[r] = *reinterpret_cast<const float4*>(&sA[ty * 4 + r][k]);
            #pragma unroll
            for (int kk = 0; kk < 4; ++kk) {
                float4 w = *reinterpret_cast<const float4*>(&sW[k + kk][tx * 4]);
                #pragma unroll
                for (int r = 0; r < 4; ++r) {
                    float av = (&a[r].x)[kk];
                    acc[r][0] += av * w.x; acc[r][1] += av * w.y;
                    acc[r][2] += av * w.z; acc[r][3] += av * w.w;
                }
            }
        }
    }
    #pragma unroll
    for (int r = 0; r < 4; ++r) {
        int gr = row0 + ty * 4 + r;
        if (gr < M) {
            float di = dinv[gr];
            float4 o = {acc[r][0] * di, acc[r][1] * di, acc[r][2] * di, acc[r][3] * di};
            *reinterpret_cast<float4*>(&C[(size_t)gr * 64 + tx * 4]) = o;
        }
    }
}

// ---------------- Aggregation (one block per node, channel per thread) ----------------
// Unrolled x8: 8 independent row gathers in flight per wave.

// h2[i][c] = relu( dinv[i]*(hs[i][c] + sum_{e in CSR[i]} hs[src_e][c]) + b1[c] )
__global__ __launch_bounds__(128) void k_agg1(const float* __restrict__ hs,
                                              const float* __restrict__ dinv,
                                              const int* __restrict__ row_ptr,
                                              const int* __restrict__ src_sorted,
                                              const float* __restrict__ b1,
                                              float* __restrict__ h2) {
    int i = blockIdx.x;
    int c = threadIdx.x;
    float acc = hs[(size_t)i * 128 + c];
    int lo = row_ptr[i], hi = row_ptr[i + 1];
    int e = lo;
    for (; e + 8 <= hi; e += 8) {
        int s0 = src_sorted[e + 0], s1 = src_sorted[e + 1];
        int s2 = src_sorted[e + 2], s3 = src_sorted[e + 3];
        int s4 = src_sorted[e + 4], s5 = src_sorted[e + 5];
        int s6 = src_sorted[e + 6], s7 = src_sorted[e + 7];
        float v0 = hs[(size_t)s0 * 128 + c];
        float v1 = hs[(size_t)s1 * 128 + c];
        float v2 = hs[(size_t)s2 * 128 + c];
        float v3 = hs[(size_t)s3 * 128 + c];
        float v4 = hs[(size_t)s4 * 128 + c];
        float v5 = hs[(size_t)s5 * 128 + c];
        float v6 = hs[(size_t)s6 * 128 + c];
        float v7 = hs[(size_t)s7 * 128 + c];
        acc += ((v0 + v1) + (v2 + v3)) + ((v4 + v5) + (v6 + v7));
    }
    if (e + 4 <= hi) {
        int s0 = src_sorted[e + 0], s1 = src_sorted[e + 1];
        int s2 = src_sorted[e + 2], s3 = src_sorted[e + 3];
        float v0 = hs[(size_t)s0 * 128 + c];
        float v1 = hs[(size_t)s1 * 128 + c];
        float v2 = hs[(size_t)s2 * 128 + c];
        float v3 = hs[(size_t)s3 * 128 + c];
        acc += (v0 + v1) + (v2 + v3);
        e += 4;
    }
    for (; e < hi; ++e) {
        int s = src_sorted[e];
        acc += hs[(size_t)s * 128 + c];
    }
    float v = dinv[i] * acc + b1[c];
    h2[(size_t)i * 128 + c] = v > 0.f ? v : 0.f;
}

// out[i][c] = dinv[i]*(zs[i][c] + sum zs[src_e][c]) + b2[c]
__global__ __launch_bounds__(64) void k_agg2(const float* __restrict__ zs,
                                             const float* __restrict__ dinv,
                                             const int* __restrict__ row_ptr,
                                             const int* __restrict__ src_sorted,
                                             const float* __restrict__ b2,
                                             float* __restrict__ out) {
    int i = blockIdx.x;
    int c = threadIdx.x;
    float acc = zs[(size_t)i * 64 + c];
    int lo = row_ptr[i], hi = row_ptr[i + 1];
    int e = lo;
    for (; e + 8 <= hi; e += 8) {
        int s0 = src_sorted[e + 0], s1 = src_sorted[e + 1];
        int s2 = src_sorted[e + 2], s3 = src_sorted[e + 3];
        int s4 = src_sorted[e + 4], s5 = src_sorted[e + 5];
        int s6 = src_sorted[e + 6], s7 = src_sorted[e + 7];
        float v0 = zs[(size_t)s0 * 64 + c];
        float v1 = zs[(size_t)s1 * 64 + c];
        float v2 = zs[(size_t)s2 * 64 + c];
        float v3 = zs[(size_t)s3 * 64 + c];
        float v4 = zs[(size_t)s4 * 64 + c];
        float v5 = zs[(size_t)s5 * 64 + c];
        float v6 = zs[(size_t)s6 * 64 + c];
        float v7 = zs[(size_t)s7 * 64 + c];
        acc += ((v0 + v1) + (v2 + v3)) + ((v4 + v5) + (v6 + v7));
    }
    if (e + 4 <= hi) {
        int s0 = src_sorted[e + 0], s1 = src_sorted[e + 1];
        int s2 = src_sorted[e + 2], s3 = src_sorted[e + 3];
        float v0 = zs[(size_t)s0 * 64 + c];
        float v1 = zs[(size_t)s1 * 64 + c];
        float v2 = zs[(size_t)s2 * 64 + c];
        float v3 = zs[(size_t)s3 * 64 + c];
        acc += (v0 + v1) + (v2 + v3);
        e += 4;
    }
    for (; e < hi; ++e) {
        int s = src_sorted[e];
        acc += zs[(size_t)s * 64 + c];
    }
    out[(size_t)i * 64 + c] = dinv[i] * acc + b2[c];
}

// ---------------- launch ----------------

static inline size_t alignup(size_t v) { return (v + 255) & ~(size_t)255; }

extern "C" void kernel_launch(void* const* d_in, const int* in_sizes, int n_in,
                              void* d_out, int out_size, void* d_ws, size_t ws_size,
                              hipStream_t stream) {
    const float* x  = (const float*)d_in[0];
    const void*  ei = d_in[1];
    const float* W1 = (const float*)d_in[2];
    const float* b1 = (const float*)d_in[3];
    const float* W2 = (const float*)d_in[4];
    const float* b2 = (const float*)d_in[5];

    const int n = in_sizes[0] / 128;   // 100000
    const int e = in_sizes[1] / 2;     // 3200000

    char* p = (char*)d_ws;
    auto take = [&](size_t bytes) { char* q = p; p += alignup(bytes); return q; };
    int*   is64       = (int*)  take(4);
    int*   src32      = (int*)  take((size_t)e * 4);
    int*   dst32      = (int*)  take((size_t)e * 4);
    int*   deg        = (int*)  take((size_t)n * 4);
    float* dinv       = (float*)take((size_t)n * 4);
    int*   row_ptr    = (int*)  take((size_t)(n + 1) * 4);
    int*   cursor     = (int*)  take((size_t)n * 4);
    int*   gsum       = (int*)  take(1024 * 4);
    int*   gbase      = (int*)  take(1024 * 4);
    int*   src_sorted = (int*)  take((size_t)e * 4);
    float* hs         = (float*)take((size_t)n * 128 * 4);
    float* h2         = (float*)take((size_t)n * 128 * 4);
    float* zs         = (float*)take((size_t)n * 64 * 4);
    if ((size_t)(p - (char*)d_ws) > ws_size) return;  // ws too small -> fail loudly

    const int nb_e = (e + 255) / 256;
    const int nb_n = (n + 255) / 256;
    const int nb_scan = (n + 1023) / 1024;   // 98 for n=100000 (must be <= 1024)

    k_detect64<<<1, 256, 0, stream>>>((const unsigned int*)ei, e, is64);
    k_init_deg<<<nb_n, 256, 0, stream>>>(deg, n);
    k_cvt_count<<<nb_e, 256, 0, stream>>>(ei, e, is64, src32, dst32, deg);
    k_scan1<<<nb_scan, 1024, 0, stream>>>(deg, row_ptr, gsum, dinv, n);
    k_scan2<<<1, 1024, 0, stream>>>(gsum, gbase, row_ptr, nb_scan, n);
    k_scan3<<<nb_n, 256, 0, stream>>>(row_ptr, cursor, gbase, n);
    k_scatter_xcd<<<2048, 256, 0, stream>>>(src32, dst32, e, cursor, src_sorted, n);

    k_gemm128<<<(n + 63) / 64, 256, 0, stream>>>(x, W1, dinv, hs, n);
    k_agg1<<<n, 128, 0, stream>>>(hs, dinv, row_ptr, src_sorted, b1, h2);
    k_gemm64<<<(n + 63) / 64, 256, 0, stream>>>(h2, W2, dinv, zs, n);
    k_agg2<<<n, 64, 0, stream>>>(zs, dinv, row_ptr, src_sorted, b2, (float*)d_out);
}

// Round 4
// 542.698 us; speedup vs baseline: 2.2083x; 1.2947x over previous
//
#include <hip/hip_runtime.h>
#include <cstdint>
#include <cstddef>

// ---- bf16 pack/unpack helpers (RNE) ----
static __device__ __forceinline__ unsigned int f2bf_rne(float f) {
    unsigned int u = __float_as_uint(f);
    unsigned int r = 0x7FFFu + ((u >> 16) & 1u);
    return (u + r) >> 16;
}
static __device__ __forceinline__ unsigned int pack_bf2(float lo, float hi) {
    return f2bf_rne(lo) | (f2bf_rne(hi) << 16);
}
static __device__ __forceinline__ float bf_lo(unsigned int w) {
    return __uint_as_float(w << 16);
}
static __device__ __forceinline__ float bf_hi(unsigned int w) {
    return __uint_as_float(w & 0xFFFF0000u);
}

// ---------------- CSR build ----------------

__global__ void k_detect64(const unsigned int* ei, int e, int* is64) {
    __shared__ int nonzero;
    if (threadIdx.x == 0) nonzero = 0;
    __syncthreads();
    for (int i = threadIdx.x; i < 4096; i += blockDim.x) {
        size_t k = (size_t)((unsigned long long)i * (unsigned long long)e / 4096ull);
        if (ei[2 * k + 1] != 0u) nonzero = 1;   // racy OR, fine
    }
    __syncthreads();
    if (threadIdx.x == 0) *is64 = nonzero ? 0 : 1;
}

__global__ void k_init_deg(int* deg, int n) {
    int i = blockIdx.x * blockDim.x + threadIdx.x;
    if (i < n) deg[i] = 1;   // self-loop
}

__global__ void k_cvt_count(const void* ei_raw, int e, const int* is64,
                            int* __restrict__ src32, int* __restrict__ dst32,
                            int* __restrict__ deg) {
    int i = blockIdx.x * blockDim.x + threadIdx.x;
    if (i >= e) return;
    int s, d;
    if (*is64) {
        const long long* p = (const long long*)ei_raw;
        s = (int)p[i];
        d = (int)p[(size_t)e + i];
    } else {
        const int* p = (const int*)ei_raw;
        s = p[i];
        d = p[(size_t)e + i];
    }
    src32[i] = s;
    dst32[i] = d;
    atomicAdd(&deg[d], 1);
}

// --- 3-phase parallel exclusive scan of (deg[i]-1), 1024 elems/block ---
__global__ __launch_bounds__(1024) void k_scan1(const int* __restrict__ deg,
                                                int* __restrict__ row_ptr,
                                                int* __restrict__ gsum,
                                                float* __restrict__ dinv, int n) {
    __shared__ int s[1024];
    int t = threadIdx.x;
    int i = blockIdx.x * 1024 + t;
    int v = 0;
    if (i < n) {
        int d = deg[i];
        v = d - 1;
        dinv[i] = rsqrtf((float)d);
    }
    s[t] = v;
    __syncthreads();
    #pragma unroll
    for (int d = 1; d < 1024; d <<= 1) {
        int tmp = (t >= d) ? s[t - d] : 0;
        __syncthreads();
        s[t] += tmp;
        __syncthreads();
    }
    if (i < n) row_ptr[i] = s[t] - v;
    if (t == 1023) gsum[blockIdx.x] = s[1023];
}

__global__ __launch_bounds__(1024) void k_scan2(const int* __restrict__ gsum,
                                                int* __restrict__ gbase,
                                                int* __restrict__ row_ptr,
                                                int nb, int n) {
    __shared__ int s[1024];
    int t = threadIdx.x;
    int v = (t < nb) ? gsum[t] : 0;
    s[t] = v;
    __syncthreads();
    #pragma unroll
    for (int d = 1; d < 1024; d <<= 1) {
        int tmp = (t >= d) ? s[t - d] : 0;
        __syncthreads();
        s[t] += tmp;
        __syncthreads();
    }
    if (t < nb) gbase[t] = s[t] - v;
    if (t == 1023) row_ptr[n] = s[1023];
}

__global__ void k_scan3(int* __restrict__ row_ptr, int* __restrict__ cursor,
                        const int* __restrict__ gbase, int n) {
    int i = blockIdx.x * blockDim.x + threadIdx.x;
    if (i >= n) return;
    int v = row_ptr[i] + gbase[i >> 10];
    row_ptr[i] = v;
    cursor[i]  = v;
}

// XCD-affinity scatter (see R2->R3: WRITE_SIZE 194MB -> full-line writebacks).
__global__ __launch_bounds__(256) void k_scatter_xcd(const int* __restrict__ src,
                                                     const int* __restrict__ dst, int e,
                                                     int* __restrict__ cursor,
                                                     int* __restrict__ src_sorted, int n) {
    int xcd = blockIdx.x & 7;
    int lo_node = (int)((long long)xcd * n / 8);
    int hi_node = (int)((long long)(xcd + 1) * n / 8);
    int nblk = gridDim.x >> 3;
    int bid  = blockIdx.x >> 3;
    int step = nblk * blockDim.x;
    for (int i = bid * blockDim.x + threadIdx.x; i < e; i += step) {
        int d = dst[i];
        int s = src[i];
        if (d >= lo_node && d < hi_node) {
            int pos = atomicAdd(&cursor[d], 1);
            src_sorted[pos] = s;
        }
    }
}

// ---------------- GEMMs (f32 VALU, LDS-tiled) ----------------
// Epilogue scales by dinv[row] and packs to bf16 pairs (halves gather bytes
// downstream: R3 k_agg1 was L3-service-bound at 786MB FETCH, 3.85 TB/s).

// hsb[m][c/2] = pack_bf16( dinv[m] * (A[m]@W)[c..c+1] ), K=128, N=128.
__global__ __launch_bounds__(256) void k_gemm128(const float* __restrict__ A,
                                                 const float* __restrict__ W,
                                                 const float* __restrict__ dinv,
                                                 unsigned int* __restrict__ hsb, int M) {
    __shared__ float sA[64][36];
    __shared__ float sW[32][128];
    int tid = threadIdx.x;
    int tx = tid & 15;   // cols tx*8 .. +7
    int ty = tid >> 4;   // rows ty*4 .. +3
    int row0 = blockIdx.x * 64;
    float acc[4][8] = {};
    for (int k0 = 0; k0 < 128; k0 += 32) {
        __syncthreads();
        for (int i = tid; i < 512; i += 256) {
            int r = i >> 3, c4 = i & 7;
            float4 v = {0.f, 0.f, 0.f, 0.f};
            int gr = row0 + r;
            if (gr < M) v = *reinterpret_cast<const float4*>(&A[(size_t)gr * 128 + k0 + c4 * 4]);
            *reinterpret_cast<float4*>(&sA[r][c4 * 4]) = v;
        }
        for (int i = tid; i < 1024; i += 256) {
            int r = i >> 5, c4 = i & 31;
            *reinterpret_cast<float4*>(&sW[r][c4 * 4]) =
                *reinterpret_cast<const float4*>(&W[(size_t)(k0 + r) * 128 + c4 * 4]);
        }
        __syncthreads();
        #pragma unroll
        for (int k = 0; k < 32; k += 4) {
            float4 a[4];
            #pragma unroll
            for (int r = 0; r < 4; ++r)
                a[r] = *reinterpret_cast<const float4*>(&sA[ty * 4 + r][k]);
            #pragma unroll
            for (int kk = 0; kk < 4; ++kk) {
                float4 w0 = *reinterpret_cast<const float4*>(&sW[k + kk][tx * 8]);
                float4 w1 = *reinterpret_cast<const float4*>(&sW[k + kk][tx * 8 + 4]);
                #pragma unroll
                for (int r = 0; r < 4; ++r) {
                    float av = (&a[r].x)[kk];
                    acc[r][0] += av * w0.x; acc[r][1] += av * w0.y;
                    acc[r][2] += av * w0.z; acc[r][3] += av * w0.w;
                    acc[r][4] += av * w1.x; acc[r][5] += av * w1.y;
                    acc[r][6] += av * w1.z; acc[r][7] += av * w1.w;
                }
            }
        }
    }
    #pragma unroll
    for (int r = 0; r < 4; ++r) {
        int gr = row0 + ty * 4 + r;
        if (gr < M) {
            float di = dinv[gr];
            uint4 o;
            o.x = pack_bf2(acc[r][0] * di, acc[r][1] * di);
            o.y = pack_bf2(acc[r][2] * di, acc[r][3] * di);
            o.z = pack_bf2(acc[r][4] * di, acc[r][5] * di);
            o.w = pack_bf2(acc[r][6] * di, acc[r][7] * di);
            *reinterpret_cast<uint4*>(&hsb[(size_t)gr * 64 + tx * 4]) = o;
        }
    }
}

// zsb[m][c/2] = pack_bf16( dinv[m] * (A[m]@W)[c..c+1] ), K=128, N=64. A is f32.
__global__ __launch_bounds__(256) void k_gemm64(const float* __restrict__ A,
                                                const float* __restrict__ W,
                                                const float* __restrict__ dinv,
                                                unsigned int* __restrict__ zsb, int M) {
    __shared__ float sA[64][36];
    __shared__ float sW[32][64];
    int tid = threadIdx.x;
    int tx = tid & 15;   // cols tx*4 .. +3
    int ty = tid >> 4;   // rows ty*4 .. +3
    int row0 = blockIdx.x * 64;
    float acc[4][4] = {};
    for (int k0 = 0; k0 < 128; k0 += 32) {
        __syncthreads();
        for (int i = tid; i < 512; i += 256) {
            int r = i >> 3, c4 = i & 7;
            float4 v = {0.f, 0.f, 0.f, 0.f};
            int gr = row0 + r;
            if (gr < M) v = *reinterpret_cast<const float4*>(&A[(size_t)gr * 128 + k0 + c4 * 4]);
            *reinterpret_cast<float4*>(&sA[r][c4 * 4]) = v;
        }
        for (int i = tid; i < 512; i += 256) {
            int r = i >> 4, c4 = i & 15;
            *reinterpret_cast<float4*>(&sW[r][c4 * 4]) =
                *reinterpret_cast<const float4*>(&W[(size_t)(k0 + r) * 64 + c4 * 4]);
        }
        __syncthreads();
        #pragma unroll
        for (int k = 0; k < 32; k += 4) {
            float4 a[4];
            #pragma unroll
            for (int r = 0; r < 4; ++r)
                a[r] = *reinterpret_cast<const float4*>(&sA[ty * 4 + r][k]);
            #pragma unroll
            for (int kk = 0; kk < 4; ++kk) {
                float4 w = *reinterpret_cast<const float4*>(&sW[k + kk][tx * 4]);
                #pragma unroll
                for (int r = 0; r < 4; ++r) {
                    float av = (&a[r].x)[kk];
                    acc[r][0] += av * w.x; acc[r][1] += av * w.y;
                    acc[r][2] += av * w.z; acc[r][3] += av * w.w;
                }
            }
        }
    }
    #pragma unroll
    for (int r = 0; r < 4; ++r) {
        int gr = row0 + ty * 4 + r;
        if (gr < M) {
            float di = dinv[gr];
            uint2 o;
            o.x = pack_bf2(acc[r][0] * di, acc[r][1] * di);
            o.y = pack_bf2(acc[r][2] * di, acc[r][3] * di);
            *reinterpret_cast<uint2*>(&zsb[(size_t)gr * 32 + tx * 2]) = o;
        }
    }
}

// ---------------- Aggregation ----------------
// bf16x2 payload: one dword per thread per row; f32 accumulate; x8 unroll
// keeps 8 row-loads in flight (R1 lesson: serial chain = latency-bound).

// h2[i][2c..2c+1] = relu( dinv[i]*(hsb_sum) + b1 ), one wave per node.
__global__ __launch_bounds__(64) void k_agg1(const unsigned int* __restrict__ hsb,
                                             const float* __restrict__ dinv,
                                             const int* __restrict__ row_ptr,
                                             const int* __restrict__ src_sorted,
                                             const float* __restrict__ b1,
                                             float* __restrict__ h2) {
    int i = blockIdx.x;
    int c = threadIdx.x;          // channel pair 2c, 2c+1
    unsigned int w = hsb[(size_t)i * 64 + c];
    float ax = bf_lo(w), ay = bf_hi(w);
    int lo = row_ptr[i], hi = row_ptr[i + 1];
    int e = lo;
    for (; e + 8 <= hi; e += 8) {
        int s0 = src_sorted[e + 0], s1 = src_sorted[e + 1];
        int s2 = src_sorted[e + 2], s3 = src_sorted[e + 3];
        int s4 = src_sorted[e + 4], s5 = src_sorted[e + 5];
        int s6 = src_sorted[e + 6], s7 = src_sorted[e + 7];
        unsigned int w0 = hsb[(size_t)s0 * 64 + c];
        unsigned int w1 = hsb[(size_t)s1 * 64 + c];
        unsigned int w2 = hsb[(size_t)s2 * 64 + c];
        unsigned int w3 = hsb[(size_t)s3 * 64 + c];
        unsigned int w4 = hsb[(size_t)s4 * 64 + c];
        unsigned int w5 = hsb[(size_t)s5 * 64 + c];
        unsigned int w6 = hsb[(size_t)s6 * 64 + c];
        unsigned int w7 = hsb[(size_t)s7 * 64 + c];
        ax += ((bf_lo(w0) + bf_lo(w1)) + (bf_lo(w2) + bf_lo(w3)))
            + ((bf_lo(w4) + bf_lo(w5)) + (bf_lo(w6) + bf_lo(w7)));
        ay += ((bf_hi(w0) + bf_hi(w1)) + (bf_hi(w2) + bf_hi(w3)))
            + ((bf_hi(w4) + bf_hi(w5)) + (bf_hi(w6) + bf_hi(w7)));
    }
    if (e + 4 <= hi) {
        int s0 = src_sorted[e + 0], s1 = src_sorted[e + 1];
        int s2 = src_sorted[e + 2], s3 = src_sorted[e + 3];
        unsigned int w0 = hsb[(size_t)s0 * 64 + c];
        unsigned int w1 = hsb[(size_t)s1 * 64 + c];
        unsigned int w2 = hsb[(size_t)s2 * 64 + c];
        unsigned int w3 = hsb[(size_t)s3 * 64 + c];
        ax += (bf_lo(w0) + bf_lo(w1)) + (bf_lo(w2) + bf_lo(w3));
        ay += (bf_hi(w0) + bf_hi(w1)) + (bf_hi(w2) + bf_hi(w3));
        e += 4;
    }
    for (; e < hi; ++e) {
        int s = src_sorted[e];
        unsigned int ws = hsb[(size_t)s * 64 + c];
        ax += bf_lo(ws);
        ay += bf_hi(ws);
    }
    float di = dinv[i];
    float2 bb = *reinterpret_cast<const float2*>(&b1[2 * c]);
    float v0 = di * ax + bb.x;
    float v1 = di * ay + bb.y;
    float2 o = {v0 > 0.f ? v0 : 0.f, v1 > 0.f ? v1 : 0.f};
    *reinterpret_cast<float2*>(&h2[(size_t)i * 128 + 2 * c]) = o;
}

// out[i][2c..2c+1] = dinv[i]*(zsb_sum) + b2; 2 nodes per 64-thread block.
__global__ __launch_bounds__(64) void k_agg2(const unsigned int* __restrict__ zsb,
                                             const float* __restrict__ dinv,
                                             const int* __restrict__ row_ptr,
                                             const int* __restrict__ src_sorted,
                                             const float* __restrict__ b2,
                                             float* __restrict__ out, int n) {
    int i = blockIdx.x * 2 + (threadIdx.x >> 5);
    int c = threadIdx.x & 31;     // channel pair 2c, 2c+1
    if (i >= n) return;
    unsigned int w = zsb[(size_t)i * 32 + c];
    float ax = bf_lo(w), ay = bf_hi(w);
    int lo = row_ptr[i], hi = row_ptr[i + 1];
    int e = lo;
    for (; e + 8 <= hi; e += 8) {
        int s0 = src_sorted[e + 0], s1 = src_sorted[e + 1];
        int s2 = src_sorted[e + 2], s3 = src_sorted[e + 3];
        int s4 = src_sorted[e + 4], s5 = src_sorted[e + 5];
        int s6 = src_sorted[e + 6], s7 = src_sorted[e + 7];
        unsigned int w0 = zsb[(size_t)s0 * 32 + c];
        unsigned int w1 = zsb[(size_t)s1 * 32 + c];
        unsigned int w2 = zsb[(size_t)s2 * 32 + c];
        unsigned int w3 = zsb[(size_t)s3 * 32 + c];
        unsigned int w4 = zsb[(size_t)s4 * 32 + c];
        unsigned int w5 = zsb[(size_t)s5 * 32 + c];
        unsigned int w6 = zsb[(size_t)s6 * 32 + c];
        unsigned int w7 = zsb[(size_t)s7 * 32 + c];
        ax += ((bf_lo(w0) + bf_lo(w1)) + (bf_lo(w2) + bf_lo(w3)))
            + ((bf_lo(w4) + bf_lo(w5)) + (bf_lo(w6) + bf_lo(w7)));
        ay += ((bf_hi(w0) + bf_hi(w1)) + (bf_hi(w2) + bf_hi(w3)))
            + ((bf_hi(w4) + bf_hi(w5)) + (bf_hi(w6) + bf_hi(w7)));
    }
    if (e + 4 <= hi) {
        int s0 = src_sorted[e + 0], s1 = src_sorted[e + 1];
        int s2 = src_sorted[e + 2], s3 = src_sorted[e + 3];
        unsigned int w0 = zsb[(size_t)s0 * 32 + c];
        unsigned int w1 = zsb[(size_t)s1 * 32 + c];
        unsigned int w2 = zsb[(size_t)s2 * 32 + c];
        unsigned int w3 = zsb[(size_t)s3 * 32 + c];
        ax += (bf_lo(w0) + bf_lo(w1)) + (bf_lo(w2) + bf_lo(w3));
        ay += (bf_hi(w0) + bf_hi(w1)) + (bf_hi(w2) + bf_hi(w3));
        e += 4;
    }
    for (; e < hi; ++e) {
        int s = src_sorted[e];
        unsigned int ws = zsb[(size_t)s * 32 + c];
        ax += bf_lo(ws);
        ay += bf_hi(ws);
    }
    float di = dinv[i];
    float2 bb = *reinterpret_cast<const float2*>(&b2[2 * c]);
    float2 o = {di * ax + bb.x, di * ay + bb.y};
    *reinterpret_cast<float2*>(&out[(size_t)i * 64 + 2 * c]) = o;
}

// ---------------- launch ----------------

static inline size_t alignup(size_t v) { return (v + 255) & ~(size_t)255; }

extern "C" void kernel_launch(void* const* d_in, const int* in_sizes, int n_in,
                              void* d_out, int out_size, void* d_ws, size_t ws_size,
                              hipStream_t stream) {
    const float* x  = (const float*)d_in[0];
    const void*  ei = d_in[1];
    const float* W1 = (const float*)d_in[2];
    const float* b1 = (const float*)d_in[3];
    const float* W2 = (const float*)d_in[4];
    const float* b2 = (const float*)d_in[5];

    const int n = in_sizes[0] / 128;   // 100000
    const int e = in_sizes[1] / 2;     // 3200000

    char* p = (char*)d_ws;
    auto take = [&](size_t bytes) { char* q = p; p += alignup(bytes); return q; };
    int*          is64       = (int*)         take(4);
    int*          src32      = (int*)         take((size_t)e * 4);
    int*          dst32      = (int*)         take((size_t)e * 4);
    int*          deg        = (int*)         take((size_t)n * 4);
    float*        dinv       = (float*)       take((size_t)n * 4);
    int*          row_ptr    = (int*)         take((size_t)(n + 1) * 4);
    int*          cursor     = (int*)         take((size_t)n * 4);
    int*          gsum       = (int*)         take(1024 * 4);
    int*          gbase      = (int*)         take(1024 * 4);
    int*          src_sorted = (int*)         take((size_t)e * 4);
    unsigned int* hsb        = (unsigned int*)take((size_t)n * 64 * 4);   // bf16x2 [n][64]
    float*        h2         = (float*)       take((size_t)n * 128 * 4);
    unsigned int* zsb        = (unsigned int*)take((size_t)n * 32 * 4);   // bf16x2 [n][32]
    if ((size_t)(p - (char*)d_ws) > ws_size) return;

    const int nb_e = (e + 255) / 256;
    const int nb_n = (n + 255) / 256;
    const int nb_scan = (n + 1023) / 1024;   // 98 for n=100000 (<=1024)

    k_detect64<<<1, 256, 0, stream>>>((const unsigned int*)ei, e, is64);
    k_init_deg<<<nb_n, 256, 0, stream>>>(deg, n);
    k_cvt_count<<<nb_e, 256, 0, stream>>>(ei, e, is64, src32, dst32, deg);
    k_scan1<<<nb_scan, 1024, 0, stream>>>(deg, row_ptr, gsum, dinv, n);
    k_scan2<<<1, 1024, 0, stream>>>(gsum, gbase, row_ptr, nb_scan, n);
    k_scan3<<<nb_n, 256, 0, stream>>>(row_ptr, cursor, gbase, n);
    k_scatter_xcd<<<2048, 256, 0, stream>>>(src32, dst32, e, cursor, src_sorted, n);

    k_gemm128<<<(n + 63) / 64, 256, 0, stream>>>(x, W1, dinv, hsb, n);
    k_agg1<<<n, 64, 0, stream>>>(hsb, dinv, row_ptr, src_sorted, b1, h2);
    k_gemm64<<<(n + 63) / 64, 256, 0, stream>>>(h2, W2, dinv, zsb, n);
    k_agg2<<<(n + 1) / 2, 64, 0, stream>>>(zsb, dinv, row_ptr, src_sorted, b2, (float*)d_out, n);
}